// Round 13
// baseline (2757.468 us; speedup 1.0000x reference)
//
#include <hip/hip_runtime.h>
#include <hip/hip_fp16.h>
#include <math.h>

#define BATCH 32
#define TLEN  1024
#define DIN   128
#define HID   512
#define NCLS  10
#define SENT64 0xFFFFFFFFFFFFFFFFull
#define POLL_CAP (1u<<17)
#define HP 36            // padded region stride (32 words + 4) in u32

typedef _Float16 hf2 __attribute__((ext_vector_type(2)));

__device__ __forceinline__ unsigned long long aload64(const unsigned long long* p) {
  return __hip_atomic_load(p, __ATOMIC_RELAXED, __HIP_MEMORY_SCOPE_AGENT);
}
__device__ __forceinline__ void astore64(unsigned long long* p, unsigned long long v) {
  __hip_atomic_store(p, v, __ATOMIC_RELAXED, __HIP_MEMORY_SCOPE_AGENT);
}

__device__ __forceinline__ float fdot2u(unsigned a, unsigned b, float c) {
#if __has_builtin(__builtin_amdgcn_fdot2)
  return __builtin_amdgcn_fdot2(__builtin_bit_cast(hf2, a),
                                __builtin_bit_cast(hf2, b), c, false);
#else
  hf2 av = __builtin_bit_cast(hf2, a), bv = __builtin_bit_cast(hf2, b);
  return c + (float)av[0] * (float)bv[0] + (float)av[1] * (float)bv[1];
#endif
}
__device__ __forceinline__ unsigned packh2(float lo, float hi) {
  __half2 h = __floats2half2_rn(lo, hi);
  return __builtin_bit_cast(unsigned, h);
}
__device__ __forceinline__ float f16of(unsigned u, int hi) {
  hf2 v = __builtin_bit_cast(hf2, u);
  return (float)v[hi];
}

// ---------- xw1[t,b,:] = x[b,t,:] @ Wx1 + b1, packed f16 pairs, all T ----------
__global__ __launch_bounds__(256) void k_xw1(
    const float* __restrict__ x, const float* __restrict__ Wx1,
    const float* __restrict__ b1, unsigned* __restrict__ xw1)   // [T*B][256] words
{
  __shared__ float xst[DIN * 4];
  const int tid  = threadIdx.x;
  const int row0 = blockIdx.x * 4;            // row = t*32 + b
  for (int idx = tid; idx < 4 * DIN; idx += 256) {
    int r = idx >> 7, d = idx & (DIN - 1);
    int row = row0 + r;
    int t = row >> 5, b = row & 31;
    xst[d * 4 + r] = x[((size_t)b * TLEN + t) * DIN + d];
  }
  __syncthreads();
  float acc[4][2];
#pragma unroll
  for (int r = 0; r < 4; ++r) { acc[r][0] = 0.f; acc[r][1] = 0.f; }
  const int j0 = 2 * tid, j1 = 2 * tid + 1;
  for (int d = 0; d < DIN; ++d) {
    float w0 = Wx1[(size_t)d * HID + j0];
    float w1 = Wx1[(size_t)d * HID + j1];
    float4 xv = *reinterpret_cast<const float4*>(&xst[d * 4]);
    acc[0][0] += xv.x * w0; acc[0][1] += xv.x * w1;
    acc[1][0] += xv.y * w0; acc[1][1] += xv.y * w1;
    acc[2][0] += xv.z * w0; acc[2][1] += xv.z * w1;
    acc[3][0] += xv.w * w0; acc[3][1] += xv.w * w1;
  }
  float bb0 = b1[j0], bb1 = b1[j1];
#pragma unroll
  for (int r = 0; r < 4; ++r)
    xw1[(size_t)(row0 + r) * 256 + tid] = packh2(acc[r][0] + bb0, acc[r][1] + bb1);
}

// ---------- persistent 3-role recurrence: FULL weight residency per CU -------
// grid 96 x 512: role = wg/32 (0=A: h1 chain, 1=B: xw2 GEMV, 2=C: h2 chain),
// b = wg%32. Thread (w,l): kg=l&7 (64 K-rows), cg=w*8+(l>>3) (8 cols).
// Weights 512KB/WG: cols 0-5 in VGPRs (192 regs/thread = 384KB/WG), cols 6-7
// in LDS (128KB, [slot][tid] conflict-free) -> ZERO per-step global weight
// traffic and only 24 LDS b128 reads/thread/step (r12: 32 + spill traffic).
// VGPR unlock: NO __launch_bounds__ (its implicit waves-per-eu clobbered the
// attribute in r9-r12 -> silent 128-cap + spill); instead
// flat_work_group_size(512,512) + waves_per_eu(2,2): 8 waves/CU -> 256 VGPRs.
// h/xw staged in parity-double-buffered LDS, regions padded to HP=36 words
// (kg-groups hit disjoint bank quads). One barrier/step. A->B, B->C links:
// sentinel-flagged full-length u64 buffers (no wrap, no throttle).
__global__ __attribute__((amdgpu_flat_work_group_size(512, 512)))
__attribute__((amdgpu_waves_per_eu(2, 2)))
void k_rnn(
    const unsigned* __restrict__ xw1,            // [T*B][256] f16-pair words
    const float* __restrict__ Wh1, const float* __restrict__ Wx2,
    const float* __restrict__ Wh2, const float* __restrict__ b2,
    unsigned long long* __restrict__ h1f,        // [T][B][128] u64 (sentinel-init)
    unsigned long long* __restrict__ xw2f,       // [T][B][128] u64 (sentinel-init)
    float* __restrict__ h2fin)                   // [B][H]
{
  const int tid  = threadIdx.x;
  const int wgid = blockIdx.x;
  const int role = wgid >> 5;
  const int b    = wgid & 31;
  const int w  = tid >> 6, l = tid & 63;
  const int kg = l & 7;                        // K-group (64 rows)
  const int cg = w * 8 + (l >> 3);             // col-group 0..63
  const int cb = 8 * cg;                       // col base (8 cols per thread)
  const int k0 = kg * 64;

  __shared__ __align__(16) uint4 wl_s[16][512];        // 131072 B (cols 6,7)
  __shared__ __align__(16) unsigned h_s[2][8 * HP];    // 2304 B
  __shared__ __align__(16) unsigned xw_s[2][8 * HP];   // 2304 B

  for (int idx = tid; idx < 2 * 8 * HP; idx += 512) {
    h_s[0][idx >= 8 * HP ? idx - 8 * HP : idx] = 0u;   // zero h_s both parities
    if (idx < 8 * HP) h_s[1][idx] = 0u;
  }

  // ---- one-time weight load ----
  const float* WS = (role == 0) ? Wh1 : ((role == 1) ? Wx2 : Wh2);
  uint4 wr[48];                                // cols 0-5 x 8 row-chunks
#pragma unroll
  for (int c = 0; c < 6; ++c) {
#pragma unroll
    for (int j = 0; j < 8; ++j) {
      const int col = cb + c, k = k0 + 8 * j;
      wr[c * 8 + j] = make_uint4(
          packh2(WS[(size_t)(k + 0) * HID + col], WS[(size_t)(k + 1) * HID + col]),
          packh2(WS[(size_t)(k + 2) * HID + col], WS[(size_t)(k + 3) * HID + col]),
          packh2(WS[(size_t)(k + 4) * HID + col], WS[(size_t)(k + 5) * HID + col]),
          packh2(WS[(size_t)(k + 6) * HID + col], WS[(size_t)(k + 7) * HID + col]));
    }
  }
#pragma unroll
  for (int c = 0; c < 2; ++c) {
#pragma unroll
    for (int j = 0; j < 8; ++j) {
      const int col = cb + 6 + c, k = k0 + 8 * j;
      wl_s[c * 8 + j][tid] = make_uint4(
          packh2(WS[(size_t)(k + 0) * HID + col], WS[(size_t)(k + 1) * HID + col]),
          packh2(WS[(size_t)(k + 2) * HID + col], WS[(size_t)(k + 3) * HID + col]),
          packh2(WS[(size_t)(k + 4) * HID + col], WS[(size_t)(k + 5) * HID + col]),
          packh2(WS[(size_t)(k + 6) * HID + col], WS[(size_t)(k + 7) * HID + col]));
    }
  }
  float4 b2lo = make_float4(0.f, 0.f, 0.f, 0.f), b2hi = b2lo;
  if (role == 1 && kg == 0) {
    b2lo = *reinterpret_cast<const float4*>(&b2[cb]);
    b2hi = *reinterpret_cast<const float4*>(&b2[cb + 4]);
  }

  const int padO = (cg >> 3) * HP + ((4 * cg) & 31);   // my 4 output words
  const int padS = (tid >> 4) * HP + ((2 * tid) & 31); // u64-stage addr (tid<128)

  uint4 huv = make_uint4(0, 0, 0, 0);          // my 8 outputs of prev step
  __syncthreads();

  for (int t = 0; t < TLEN; ++t) {
    const int p = t & 1;

    // ---------------- phase 1 (pre-barrier): stage h + xw -------------------
    if (role == 0) {
      if (kg == 0 && t > 0) *(uint4*)&h_s[p][padO] = huv;        // h1(t-1)
      if (tid < 128) {
        unsigned long long xv =
            *(const unsigned long long*)&xw1[((size_t)t * BATCH + b) * 256 + 2 * tid];
        *(unsigned long long*)&xw_s[p][padS] = xv;               // xw1(t)
      }
    } else if (role == 1) {
      if (tid < 128) {
        const unsigned long long* ph = &h1f[((size_t)t * BATCH + b) * 128 + tid];
        unsigned long long pv = aload64(ph);
        unsigned it = 0;
        while (pv == SENT64 && ++it < POLL_CAP) pv = aload64(ph);
        if (pv == SENT64) pv = 0;
        *(unsigned long long*)&h_s[p][padS] = pv;                // h1(t)
      }
    } else {
      if (kg == 0 && t > 0) *(uint4*)&h_s[p][padO] = huv;        // h2(t-1)
      if (tid < 128) {
        const unsigned long long* ph = &xw2f[((size_t)t * BATCH + b) * 128 + tid];
        unsigned long long pv = aload64(ph);
        unsigned it = 0;
        while (pv == SENT64 && ++it < POLL_CAP) pv = aload64(ph);
        if (pv == SENT64) pv = 0;
        *(unsigned long long*)&xw_s[p][padS] = pv;               // xw2(t)
      }
    }

    __syncthreads();   // h_s[p]/xw_s[p] ready

    // ---------------- phase 2: publish prev step's output -------------------
    if (kg == 0 && t > 0) {
      unsigned long long u0 = ((unsigned long long)huv.y << 32) | huv.x;
      unsigned long long u1 = ((unsigned long long)huv.w << 32) | huv.z;
      if (role == 0) {
        astore64(&h1f[((size_t)(t - 1) * BATCH + b) * 128 + 2 * cg], u0);
        astore64(&h1f[((size_t)(t - 1) * BATCH + b) * 128 + 2 * cg + 1], u1);
      } else if (role == 1) {
        astore64(&xw2f[((size_t)(t - 1) * BATCH + b) * 128 + 2 * cg], u0);
        astore64(&xw2f[((size_t)(t - 1) * BATCH + b) * 128 + 2 * cg + 1], u1);
      }
    }

    // ---------------- phase 3: dot over 64 K-rows, 8 cols -------------------
    float acc[8];
#pragma unroll
    for (int c = 0; c < 8; ++c) acc[c] = 0.f;
#pragma unroll
    for (int j = 0; j < 8; ++j) {
      uint4 hv = *reinterpret_cast<const uint4*>(&h_s[p][kg * HP + 4 * j]);
#pragma unroll
      for (int c = 0; c < 6; ++c) {
        uint4 wv = wr[c * 8 + j];
        acc[c] = fdot2u(hv.x, wv.x, acc[c]);
        acc[c] = fdot2u(hv.y, wv.y, acc[c]);
        acc[c] = fdot2u(hv.z, wv.z, acc[c]);
        acc[c] = fdot2u(hv.w, wv.w, acc[c]);
      }
      uint4 c6 = wl_s[j][tid];
      uint4 c7 = wl_s[8 + j][tid];
      acc[6] = fdot2u(hv.x, c6.x, acc[6]);
      acc[6] = fdot2u(hv.y, c6.y, acc[6]);
      acc[6] = fdot2u(hv.z, c6.z, acc[6]);
      acc[6] = fdot2u(hv.w, c6.w, acc[6]);
      acc[7] = fdot2u(hv.x, c7.x, acc[7]);
      acc[7] = fdot2u(hv.y, c7.y, acc[7]);
      acc[7] = fdot2u(hv.z, c7.z, acc[7]);
      acc[7] = fdot2u(hv.w, c7.w, acc[7]);
    }
#pragma unroll
    for (int c = 0; c < 8; ++c) {
      acc[c] += __shfl_xor(acc[c], 1);
      acc[c] += __shfl_xor(acc[c], 2);
      acc[c] += __shfl_xor(acc[c], 4);
    }

    // ---------------- phase 4: finalize (kg==0 lanes own the 8 cols) --------
    if (kg == 0) {
      if (role == 1) {
        huv = make_uint4(packh2(acc[0] + b2lo.x, acc[1] + b2lo.y),
                         packh2(acc[2] + b2lo.z, acc[3] + b2lo.w),
                         packh2(acc[4] + b2hi.x, acc[5] + b2hi.y),
                         packh2(acc[6] + b2hi.z, acc[7] + b2hi.w));
      } else {
        uint4 xv4 = *reinterpret_cast<const uint4*>(&xw_s[p][padO]);
        float h0 = tanhf(acc[0] + f16of(xv4.x, 0));
        float h1 = tanhf(acc[1] + f16of(xv4.x, 1));
        float h2 = tanhf(acc[2] + f16of(xv4.y, 0));
        float h3 = tanhf(acc[3] + f16of(xv4.y, 1));
        float h4 = tanhf(acc[4] + f16of(xv4.z, 0));
        float h5 = tanhf(acc[5] + f16of(xv4.z, 1));
        float h6 = tanhf(acc[6] + f16of(xv4.w, 0));
        float h7 = tanhf(acc[7] + f16of(xv4.w, 1));
        huv = make_uint4(packh2(h0, h1), packh2(h2, h3),
                         packh2(h4, h5), packh2(h6, h7));
        if (role == 2 && t == TLEN - 1) {
          *reinterpret_cast<float4*>(&h2fin[(size_t)b * HID + cb]) =
              make_float4(h0, h1, h2, h3);
          *reinterpret_cast<float4*>(&h2fin[(size_t)b * HID + cb + 4]) =
              make_float4(h4, h5, h6, h7);
        }
      }
    }
  }
  // epilogue: publish the final step's output
  if (kg == 0 && role != 2) {
    unsigned long long u0 = ((unsigned long long)huv.y << 32) | huv.x;
    unsigned long long u1 = ((unsigned long long)huv.w << 32) | huv.z;
    unsigned long long* dst = (role == 0) ? h1f : xw2f;
    astore64(&dst[((size_t)(TLEN - 1) * BATCH + b) * 128 + 2 * cg], u0);
    astore64(&dst[((size_t)(TLEN - 1) * BATCH + b) * 128 + 2 * cg + 1], u1);
  }
}

// ---------- softmax(h2 @ Wo + bo) ----------
__global__ __launch_bounds__(640) void k_head(
    const float* __restrict__ h2, const float* __restrict__ Wo,
    const float* __restrict__ bo, float* __restrict__ out)
{
  __shared__ float lg[16];
  const int b = blockIdx.x;
  const int c = threadIdx.x >> 6;   // wave per class
  const int l = threadIdx.x & 63;
  float p = 0.f;
#pragma unroll
  for (int i = 0; i < 8; ++i) {
    int k = l + 64 * i;
    p += h2[(size_t)b * HID + k] * Wo[(size_t)k * NCLS + c];
  }
  for (int off = 32; off; off >>= 1) p += __shfl_down(p, off);
  if (l == 0) lg[c] = p + bo[c];
  __syncthreads();
  if (threadIdx.x == 0) {
    float m = lg[0];
    for (int i = 1; i < NCLS; ++i) m = fmaxf(m, lg[i]);
    float e[NCLS];
    float s = 0.f;
    for (int i = 0; i < NCLS; ++i) { e[i] = expf(lg[i] - m); s += e[i]; }
    for (int i = 0; i < NCLS; ++i) out[(size_t)b * NCLS + i] = e[i] / s;
  }
}

extern "C" void kernel_launch(void* const* d_in, const int* in_sizes, int n_in,
                              void* d_out, int out_size, void* d_ws, size_t ws_size,
                              hipStream_t stream)
{
  (void)in_sizes; (void)n_in; (void)out_size; (void)ws_size;
  const float* x   = (const float*)d_in[0];
  const float* Wx1 = (const float*)d_in[1];
  const float* Wh1 = (const float*)d_in[2];
  const float* b1  = (const float*)d_in[3];
  const float* Wx2 = (const float*)d_in[4];
  const float* Wh2 = (const float*)d_in[5];
  const float* b2  = (const float*)d_in[6];
  const float* Wo  = (const float*)d_in[7];
  const float* bo  = (const float*)d_in[8];
  float* out = (float*)d_out;

  char* ws = (char*)d_ws;
  size_t o = 0;
  unsigned* xw1 = (unsigned*)(ws + o);              o += (size_t)TLEN * BATCH * 256 * 4;  // 32MB
  unsigned long long* h1f  = (unsigned long long*)(ws + o); o += (size_t)TLEN * BATCH * 128 * 8; // 32MB
  unsigned long long* xw2f = (unsigned long long*)(ws + o); o += (size_t)TLEN * BATCH * 128 * 8; // 32MB
  float* h2fin = (float*)(ws + o);                  o += (size_t)BATCH * HID * 4;

  // sentinel-init the two link buffers (contiguous, 64MB)
  hipMemsetAsync(h1f, 0xFF, (size_t)2 * TLEN * BATCH * 128 * 8, stream);

  k_xw1<<<TLEN * BATCH / 4, 256, 0, stream>>>(x, Wx1, b1, xw1);
  k_rnn<<<96, 512, 0, stream>>>(xw1, Wh1, Wx2, Wh2, b2, h1f, xw2f, h2fin);
  k_head<<<BATCH, 640, 0, stream>>>(h2fin, Wo, bo, out);
}